// Round 12
// baseline (194.695 us; speedup 1.0000x reference)
//
#include <hip/hip_runtime.h>

#define N_NODES 2048
#define C_CH    128
#define N_SPEC  10

// --- symmetric-reduced coefficient page per (species, channel) ---------------
// Global layout (prep-verified): main[219][8] | tail[219], pad to 2048 floats.
// Monomial order: m=0..164 sorted triples a<=b<=j (lex), 165..209 sorted pairs
// a<=b (lex), 210..218 singles a.
#define PAGE2   2048
#define MAIN_F  1752          // 219*8

#define CG_OFF_B  (256 * 1024)
#define CG_BYTES  ((size_t)N_SPEC * C_CH * PAGE2 * 4)

struct Params {
    const float* U3[3]; const float* W3[3];
    const float* U2[3]; const float* W2[3];
    const float* U1[3]; const float* W1[3];
};

// ---------------------------------------------------------------------------
// Kernel 1 (fused prep) — coef part verified rounds 7/9/10; bucket block uses
// per-wave ballot aggregation (1 atomic per wave/species/chunk instead of
// 2048 contended atomics). Bucket order within a species is arbitrary and
// irrelevant to correctness (eval treats the list as a set).
// ---------------------------------------------------------------------------
template <int ORD, int MUL, int IRD, int IOFF, int MOFF>
__device__ inline void coefRegion3(const float* __restrict__ u,
                                   const float* __restrict__ W,
                                   int s, int row0, int rows, int c0,
                                   float* __restrict__ Cg,
                                   float* __restrict__ sU, float* __restrict__ sW) {
    const int tid = threadIdx.x;
    const int mi  = MUL * IRD;
    const int nfl = rows * mi;
    for (int f = tid; f < nfl; f += 128) {
        const int rr  = f / mi;
        const int rem = f - rr * mi;
        const int n   = row0 + rr;
        float acc;
        if (ORD == 3) {
            int nn = n, aa = 0;
            while (true) { int ca = (9 - aa) * (10 - aa) / 2; if (nn < ca) break; nn -= ca; ++aa; }
            int bb = aa;
            while (true) { int cb = 9 - bb; if (nn < cb) break; nn -= cb; ++bb; }
            const int jj = bb + nn;
            int L[6];
            L[0] = (aa * 9 + bb) * 9 + jj; L[1] = (aa * 9 + jj) * 9 + bb;
            L[2] = (bb * 9 + aa) * 9 + jj; L[3] = (bb * 9 + jj) * 9 + aa;
            L[4] = (jj * 9 + aa) * 9 + bb; L[5] = (jj * 9 + bb) * 9 + aa;
            acc = 0.f;
            for (int m = 0; m < 6; ++m) {
                bool dup = false;
                for (int q = 0; q < m; ++q) dup = dup || (L[q] == L[m]);
                if (!dup) acc += u[L[m] * mi + rem];
            }
        } else if (ORD == 2) {
            int nn = n, aa = 0;
            while (true) { int cb = 9 - aa; if (nn < cb) break; nn -= cb; ++aa; }
            const int bb = aa + nn;
            acc = u[(aa * 9 + bb) * mi + rem];
            if (aa != bb) acc += u[(bb * 9 + aa) * mi + rem];
        } else {
            acc = u[n * mi + rem];
        }
        sU[f] = acc;
    }
    for (int idx = tid; idx < MUL * 32; idx += 128) {
        const int k = idx >> 5, cc = idx & 31;
        sW[idx] = W[(s * MUL + k) * C_CH + c0 + cc];
    }
    __syncthreads();

    const int nel = rows * IRD;
    for (int f = tid; f < nel; f += 128) {
        const int rr = f / IRD;
        const int il = f - rr * IRD;
        float uv[MUL];
#pragma unroll
        for (int k = 0; k < MUL; ++k) uv[k] = sU[(rr * MUL + k) * IRD + il];
        const int m = MOFF + row0 + rr;
        const int i = IOFF + il;
        const int off = (i < 8) ? (m * 8 + i) : (MAIN_F + m);
        for (int cc = 0; cc < 32; ++cc) {
            float acc = 0.f;
#pragma unroll
            for (int k = 0; k < MUL; ++k) acc += uv[k] * sW[k * 32 + cc];
            Cg[(size_t)(s * C_CH + c0 + cc) * PAGE2 + off] = acc;
        }
    }
}

__global__ __launch_bounds__(128) void prep_kernel(Params p, const int* __restrict__ index,
                                                   int* __restrict__ counts,
                                                   int* __restrict__ lists,
                                                   float* __restrict__ Cg) {
    const int bx = blockIdx.x;
    if (bx == N_SPEC * 120) {   // --- bucket block (ballot-aggregated) ---
        __shared__ int sc[N_SPEC];
        const int tid  = threadIdx.x;
        const int lane = tid & 63;
        if (tid < N_SPEC) sc[tid] = 0;
        __syncthreads();
        for (int n0 = 0; n0 < N_NODES; n0 += 128) {
            const int n = n0 + tid;
            const int myS = index[n];
#pragma unroll 1
            for (int s = 0; s < N_SPEC; ++s) {
                const unsigned long long m = __ballot(myS == s);
                if (myS == s) {
                    const int prior  = __popcll(m & ((1ull << lane) - 1ull));
                    const int leader = __ffsll((long long)m) - 1;
                    int base = 0;
                    if (lane == leader) base = atomicAdd(&sc[s], __popcll(m));
                    base = __shfl(base, leader);
                    lists[s * N_NODES + base + prior] = n;
                }
            }
        }
        __syncthreads();
        if (tid < N_SPEC) counts[tid] = sc[tid];
        return;
    }
    __shared__ float sU[1560];
    __shared__ float sW[13 * 32];
    const int s   = bx / 120;
    const int rem = bx % 120;
    const int t   = rem / 4;
    const int c0  = (rem % 4) * 32;

    if (t < 7) {
        int rel = t, row0 = rel * 24, rows = (rel == 6) ? 21 : 24;
        coefRegion3<3, 10, 1, 0, 0>(p.U3[0], p.W3[0], s, row0, rows, c0, Cg, sU, sW);
    } else if (t < 14) {
        int rel = t - 7, row0 = rel * 24, rows = (rel == 6) ? 21 : 24;
        coefRegion3<3, 11, 3, 1, 0>(p.U3[1], p.W3[1], s, row0, rows, c0, Cg, sU, sW);
    } else if (t < 21) {
        int rel = t - 14, row0 = rel * 24, rows = (rel == 6) ? 21 : 24;
        coefRegion3<3, 13, 5, 4, 0>(p.U3[2], p.W3[2], s, row0, rows, c0, Cg, sU, sW);
    } else if (t < 23) {
        int rel = t - 21, row0 = rel * 24, rows = (rel == 1) ? 21 : 24;
        coefRegion3<2, 3, 1, 0, 165>(p.U2[0], p.W2[0], s, row0, rows, c0, Cg, sU, sW);
    } else if (t < 25) {
        int rel = t - 23, row0 = rel * 24, rows = (rel == 1) ? 21 : 24;
        coefRegion3<2, 2, 3, 1, 165>(p.U2[1], p.W2[1], s, row0, rows, c0, Cg, sU, sW);
    } else if (t < 27) {
        int rel = t - 25, row0 = rel * 24, rows = (rel == 1) ? 21 : 24;
        coefRegion3<2, 3, 5, 4, 165>(p.U2[2], p.W2[2], s, row0, rows, c0, Cg, sU, sW);
    } else if (t == 27) {
        coefRegion3<1, 1, 1, 0, 210>(p.U1[0], p.W1[0], s, 0, 9, c0, Cg, sU, sW);
    } else if (t == 28) {
        coefRegion3<1, 1, 3, 1, 210>(p.U1[1], p.W1[1], s, 0, 9, c0, Cg, sU, sW);
    } else {
        coefRegion3<1, 1, 5, 4, 210>(p.U1[2], p.W1[2], s, 0, 9, c0, Cg, sU, sW);
    }
}

// dynamic index into a register array: cndmask chain (selector wave-uniform)
__device__ inline float selx(const float x[9], int a) {
    float r = x[0];
    r = (a == 1) ? x[1] : r; r = (a == 2) ? x[2] : r; r = (a == 3) ? x[3] : r;
    r = (a == 4) ? x[4] : r; r = (a == 5) ? x[5] : r; r = (a == 6) ? x[6] : r;
    r = (a == 7) ? x[7] : r; r = (a == 8) ? x[8] : r;
    return r;
}

// ---------------------------------------------------------------------------
// Kernel 2: evaluation — SPLIT-PLANE WAVES on the round-10 no-spill skeleton.
// Page staged as [219][16] floats: {c0..c3, c8, -,-,-, c4..c7, c8, -,-,-}
// (+1 pad row for prefetch). 128 threads = 2 waves; BOTH waves process the
// same 256 node slots (4 nodes/thread); wave w reads its half-plane at
// uniform float offset w*8 -> per monomial per wave only 1 ds_read_b128 +
// 1 ds_read_b32 serving 256 node-channels (round 10: 2xb128+b32 for 128).
// Rolled loops + running pointer + depth-1 prefetch (proven no-spill regime;
// full unrolls spilled in rounds 3/7/8/9). Staging writes are float4-flat
// (consecutive lanes -> consecutive float4s): round 8's 473K bank conflicts
// came from its 64B-stride staging, not the broadcast reads.
// Wave0 writes out[0..3]+out[8]; wave1 writes out[4..7] (o8 redundant there).
// ---------------------------------------------------------------------------
__global__ __launch_bounds__(128) void sc_eval_kernel(const float* __restrict__ nf,
                                                      const int* __restrict__ counts,
                                                      const int* __restrict__ lists,
                                                      const float* __restrict__ Cg,
                                                      float* __restrict__ out) {
    __shared__ __align__(16) float sP[220 * 16];   // 220: prefetch pad row
    const int s = blockIdx.x / C_CH;   // 128 consecutive blocks share a species
    const int c = blockIdx.x % C_CH;
    const float* __restrict__ Cp = Cg + (size_t)(s * C_CH + c) * PAGE2;

    {   // conflict-free staging: thread d writes float4 #d of sP
        const float4* Gv = (const float4*)Cp;
        float4* Sv = (float4*)sP;
        for (int d = threadIdx.x; d < 219 * 4; d += 128) {
            const int row = d >> 2, part = d & 3;
            float4 v;
            if (part == 0)      v = Gv[row * 2];
            else if (part == 2) v = Gv[row * 2 + 1];
            else {
                const float t = Cp[MAIN_F + row];
                v = make_float4(t, 0.f, 0.f, 0.f);
            }
            Sv[d] = v;
        }
    }
    __syncthreads();

    const int cnt  = counts[s];
    const int wid  = threadIdx.x >> 6;       // wave id: 0 or 1 (wave-uniform)
    const int lane = threadIdx.x & 63;
    const int woff = wid * 8;                // float offset into half-plane

    for (int base = 0; base < cnt; base += 256) {
        int mm[4];
        float x[4][9];
#pragma unroll
        for (int u = 0; u < 4; ++u) {
            const int i = base + lane + 64 * u;          // both waves: same slots
            mm[u] = (i < cnt) ? lists[s * N_NODES + i] : -1;
            const float* xp = nf + ((long)(mm[u] < 0 ? 0 : mm[u]) * C_CH + c) * 9;
#pragma unroll
            for (int j = 0; j < 9; ++j) x[u][j] = xp[j];
        }

        float4 oM[4];
        float  o8[4];
#pragma unroll
        for (int u = 0; u < 4; ++u) { oM[u] = {0, 0, 0, 0}; o8[u] = 0.f; }

        // stream pointers into [219][16] layout (advance 16 floats/monomial)
        const float* p3 = sP + woff;
        const float* p2 = sP + 165 * 16 + woff;
        const float* p1 = sP + 210 * 16 + woff;

        // preload stream heads
        float4 c3 = *(const float4*)p3; float c38 = p3[4];
        float4 c2 = *(const float4*)p2; float c28 = p2[4];
        float4 c1 = *(const float4*)p1; float c18 = p1[4];

#pragma unroll 1
        for (int a = 0; a < 9; ++a) {
            float xa[4];
#pragma unroll
            for (int u = 0; u < 4; ++u) xa[u] = selx(x[u], a);
            {   // S1 monomial (prefetch next single, then use current)
                const float4 n1 = *(const float4*)(p1 + 16); const float n18 = p1[20];
#pragma unroll
                for (int u = 0; u < 4; ++u) { oM[u] += c1 * xa[u]; o8[u] += c18 * xa[u]; }
                c1 = n1; c18 = n18; p1 += 16;
            }
#pragma unroll 1
            for (int b = a; b < 9; ++b) {
                float xb[4];
#pragma unroll
                for (int u = 0; u < 4; ++u) xb[u] = selx(x[u], b) * xa[u];
                {   // S2 monomial
                    const float4 n2 = *(const float4*)(p2 + 16); const float n28 = p2[20];
#pragma unroll
                    for (int u = 0; u < 4; ++u) { oM[u] += c2 * xb[u]; o8[u] += c28 * xb[u]; }
                    c2 = n2; c28 = n28; p2 += 16;
                }
#pragma unroll 1
                for (int j = b; j < 9; ++j) {   // S3 monomials
                    const float4 n3 = *(const float4*)(p3 + 16); const float n38 = p3[20];
#pragma unroll
                    for (int u = 0; u < 4; ++u) {
                        const float mn = selx(x[u], j) * xb[u];
                        oM[u] += c3 * mn; o8[u] += c38 * mn;
                    }
                    c3 = n3; c38 = n38; p3 += 16;
                }
            }
        }

        if (wid == 0) {
#pragma unroll
            for (int u = 0; u < 4; ++u) {
                if (mm[u] >= 0) {
                    float* op = out + ((long)mm[u] * C_CH + c) * 9;
                    op[0] = oM[u].x; op[1] = oM[u].y; op[2] = oM[u].z; op[3] = oM[u].w;
                    op[8] = o8[u];
                }
            }
        } else {
#pragma unroll
            for (int u = 0; u < 4; ++u) {
                if (mm[u] >= 0) {
                    float* op = out + ((long)mm[u] * C_CH + c) * 9;
                    op[4] = oM[u].x; op[5] = oM[u].y; op[6] = oM[u].z; op[7] = oM[u].w;
                }
            }
        }
    }
}

// ---------------------------------------------------------------------------
// Fallback path (round-0 verified kernels) in case ws_size is too small.
// ---------------------------------------------------------------------------
__global__ __launch_bounds__(1024) void bucket_kernel(const int* __restrict__ index,
                                                      int* __restrict__ counts,
                                                      int* __restrict__ lists) {
    __shared__ int sc[N_SPEC];
    const int tid = threadIdx.x;
    if (tid < N_SPEC) sc[tid] = 0;
    __syncthreads();
    for (int n = tid; n < N_NODES; n += blockDim.x) {
        int s = index[n];
        int pos = atomicAdd(&sc[s], 1);
        lists[s * N_NODES + pos] = n;
    }
    __syncthreads();
    if (tid < N_SPEC) counts[tid] = sc[tid];
}

template <int NAB, int MUL, int IRD, int IOFF>
__device__ inline void buildC(const float* __restrict__ u, const float* __restrict__ w,
                              int s, int c, float* __restrict__ sMain, float* __restrict__ sB) {
    const int tid = threadIdx.x;
    const float* wp = w + (s * MUL) * C_CH + c;
    for (int e = tid; e < NAB * IRD; e += 128) {
        int abj = e / IRD;
        int il  = e - abj * IRD;
        const float* up = u + (abj * MUL) * IRD + il;
        float acc = 0.f;
#pragma unroll
        for (int k = 0; k < MUL; ++k)
            acc += up[k * IRD] * wp[k * C_CH];
        int i = IOFF + il;
        if (i < 8) sMain[abj * 8 + i] = acc;
        else       sB[abj] = acc;
    }
}

__global__ __launch_bounds__(128) void sc_kernel(const float* __restrict__ nf,
                                                 const int* __restrict__ counts,
                                                 const int* __restrict__ lists,
                                                 Params p,
                                                 float* __restrict__ out) {
    __shared__ __align__(16) float sC3[729 * 8];
    __shared__ float sC3b[729];
    __shared__ __align__(16) float sC2[81 * 8];
    __shared__ float sC2b[81];
    __shared__ __align__(16) float sC1[9 * 8];
    __shared__ float sC1b[9];

    const int s = blockIdx.x % N_SPEC;
    const int c = blockIdx.x / N_SPEC;
    const int tid = threadIdx.x;

    buildC<729, 10, 1, 0>(p.U3[0], p.W3[0], s, c, sC3, sC3b);
    buildC<729, 11, 3, 1>(p.U3[1], p.W3[1], s, c, sC3, sC3b);
    buildC<729, 13, 5, 4>(p.U3[2], p.W3[2], s, c, sC3, sC3b);
    buildC<81, 3, 1, 0>(p.U2[0], p.W2[0], s, c, sC2, sC2b);
    buildC<81, 2, 3, 1>(p.U2[1], p.W2[1], s, c, sC2, sC2b);
    buildC<81, 3, 5, 4>(p.U2[2], p.W2[2], s, c, sC2, sC2b);
    buildC<9, 1, 1, 0>(p.U1[0], p.W1[0], s, c, sC1, sC1b);
    buildC<9, 1, 3, 1>(p.U1[1], p.W1[1], s, c, sC1, sC1b);
    buildC<9, 1, 5, 4>(p.U1[2], p.W1[2], s, c, sC1, sC1b);
    __syncthreads();

    const int cnt = counts[s];
    const float4* C3v = (const float4*)sC3;
    const float4* C2v = (const float4*)sC2;
    const float4* C1v = (const float4*)sC1;

    for (int base = 0; base < cnt; base += 256) {
        const int i0 = base + tid;
        const int i1 = base + 128 + tid;
        const int m0 = (i0 < cnt) ? lists[s * N_NODES + i0] : -1;
        const int m1 = (i1 < cnt) ? lists[s * N_NODES + i1] : -1;

        const float* x0p = nf + ((long)(m0 < 0 ? 0 : m0) * C_CH + c) * 9;
        const float* x1p = nf + ((long)(m1 < 0 ? 0 : m1) * C_CH + c) * 9;
        float x0[9], x1[9];
#pragma unroll
        for (int j = 0; j < 9; ++j) { x0[j] = x0p[j]; x1[j] = x1p[j]; }

        float4 o0a = {0, 0, 0, 0}, o0b = {0, 0, 0, 0};
        float4 o1a = {0, 0, 0, 0}, o1b = {0, 0, 0, 0};
        float o08 = 0.f, o18 = 0.f;

#pragma unroll 1
        for (int a = 0; a < 9; ++a) {
            const float xa0 = selx(x0, a);
            const float xa1 = selx(x1, a);
            const float4 c1a = C1v[a * 2], c1b = C1v[a * 2 + 1];
            const float  c18 = sC1b[a];
            float4 q0a = c1a, q0b = c1b; float q08 = c18;
            float4 q1a = c1a, q1b = c1b; float q18 = c18;
#pragma unroll
            for (int b = 0; b < 9; ++b) {
                const int ab = a * 9 + b;
                const float4 c2a = C2v[ab * 2], c2b = C2v[ab * 2 + 1];
                const float  c28 = sC2b[ab];
                float4 t0a = c2a, t0b = c2b; float t08 = c28;
                float4 t1a = c2a, t1b = c2b; float t18 = c28;
#pragma unroll
                for (int j = 0; j < 9; ++j) {
                    const int abj = ab * 9 + j;
                    const float4 ca = C3v[abj * 2];
                    const float4 cb = C3v[abj * 2 + 1];
                    const float  c8 = sC3b[abj];
                    t0a += ca * x0[j]; t0b += cb * x0[j]; t08 += c8 * x0[j];
                    t1a += ca * x1[j]; t1b += cb * x1[j]; t18 += c8 * x1[j];
                }
                q0a += t0a * x0[b]; q0b += t0b * x0[b]; q08 += t08 * x0[b];
                q1a += t1a * x1[b]; q1b += t1b * x1[b]; q18 += t18 * x1[b];
            }
            o0a += q0a * xa0; o0b += q0b * xa0; o08 += q08 * xa0;
            o1a += q1a * xa1; o1b += q1b * xa1; o18 += q18 * xa1;
        }

        if (m0 >= 0) {
            float* op = out + ((long)m0 * C_CH + c) * 9;
            op[0] = o0a.x; op[1] = o0a.y; op[2] = o0a.z; op[3] = o0a.w;
            op[4] = o0b.x; op[5] = o0b.y; op[6] = o0b.z; op[7] = o0b.w;
            op[8] = o08;
        }
        if (m1 >= 0) {
            float* op = out + ((long)m1 * C_CH + c) * 9;
            op[0] = o1a.x; op[1] = o1a.y; op[2] = o1a.z; op[3] = o1a.w;
            op[4] = o1b.x; op[5] = o1b.y; op[6] = o1b.z; op[7] = o1b.w;
            op[8] = o18;
        }
    }
}

// ---------------------------------------------------------------------------
extern "C" void kernel_launch(void* const* d_in, const int* in_sizes, int n_in,
                              void* d_out, int out_size, void* d_ws, size_t ws_size,
                              hipStream_t stream) {
    const float* nf   = (const float*)d_in[0];
    const int* index  = (const int*)d_in[1];

    Params p;
    p.U3[0] = (const float*)d_in[2];  p.W3[0] = (const float*)d_in[3];
    p.U3[1] = (const float*)d_in[4];  p.W3[1] = (const float*)d_in[5];
    p.U3[2] = (const float*)d_in[6];  p.W3[2] = (const float*)d_in[7];
    p.U2[0] = (const float*)d_in[8];  p.W2[0] = (const float*)d_in[9];
    p.U2[1] = (const float*)d_in[10]; p.W2[1] = (const float*)d_in[11];
    p.U2[2] = (const float*)d_in[12]; p.W2[2] = (const float*)d_in[13];
    p.U1[0] = (const float*)d_in[14]; p.W1[0] = (const float*)d_in[15];
    p.U1[1] = (const float*)d_in[16]; p.W1[1] = (const float*)d_in[17];
    p.U1[2] = (const float*)d_in[18]; p.W1[2] = (const float*)d_in[19];

    int* counts = (int*)d_ws;        // 16 ints
    int* lists  = (int*)d_ws + 16;   // 10 * 2048 ints, ends at 81,984 B

    if (ws_size >= (size_t)CG_OFF_B + CG_BYTES) {
        float* Cg = (float*)((char*)d_ws + CG_OFF_B);
        prep_kernel<<<N_SPEC * 120 + 1, 128, 0, stream>>>(p, index, counts, lists, Cg);
        sc_eval_kernel<<<N_SPEC * C_CH, 128, 0, stream>>>(nf, counts, lists, Cg,
                                                          (float*)d_out);
    } else {
        bucket_kernel<<<1, 1024, 0, stream>>>(index, counts, lists);
        sc_kernel<<<N_SPEC * C_CH, 128, 0, stream>>>(nf, counts, lists, p,
                                                     (float*)d_out);
    }
}